// Round 1
// 726.986 us; speedup vs baseline: 1.1943x; 1.1943x over previous
//
#include <hip/hip_runtime.h>
#include <math.h>

// Problem constants (B, S, D, MAXOBJ) = (512, 77, 2048, 4)
#define B_ 512
#define S_ 77
#define D_ 2048
#define EPS_ 1e-5f

typedef __attribute__((ext_vector_type(8))) short bf16x8;
typedef __attribute__((ext_vector_type(4))) float f32x4;

// fp32 -> bf16 bits, round-to-nearest-even
__device__ __forceinline__ unsigned short f2bf(float f) {
  union { float f; unsigned u; } x; x.f = f;
  return (unsigned short)((x.u + 0x7FFFu + ((x.u >> 16) & 1u)) >> 16);
}

// block=256 reduction of (sum, sumsq)
__device__ __forceinline__ void blockReduce2(float& a, float& b, float* sbuf) {
  #pragma unroll
  for (int off = 32; off > 0; off >>= 1) {
    a += __shfl_down(a, off, 64);
    b += __shfl_down(b, off, 64);
  }
  int lane = threadIdx.x & 63, wid = threadIdx.x >> 6;
  if (lane == 0) { sbuf[wid * 2] = a; sbuf[wid * 2 + 1] = b; }
  __syncthreads();
  if (threadIdx.x == 0) {
    float sa = 0.f, sb = 0.f;
    #pragma unroll
    for (int w = 0; w < 4; w++) { sa += sbuf[w * 2]; sb += sbuf[w * 2 + 1]; }
    sbuf[8] = sa; sbuf[9] = sb;
  }
  __syncthreads();
  a = sbuf[8]; b = sbuf[9];
}

// ---------------- weight convert+transpose: W[K][2048] f32 -> Wt[2048][K] bf16 ----------------
// One launch handles all 4 weights via blockIdx.z. N is always 2048.
__global__ __launch_bounds__(256)
void wcvt_kernel(const float* __restrict__ w1, const float* __restrict__ w2,
                 const float* __restrict__ w3, const float* __restrict__ w4,
                 unsigned short* __restrict__ o1, unsigned short* __restrict__ o2,
                 unsigned short* __restrict__ o3, unsigned short* __restrict__ o4) {
  __shared__ unsigned short T[64 * 72];
  const int z = blockIdx.z;
  const int K = (z == 0) ? 4096 : 2048;
  if ((int)blockIdx.y * 64 >= K) return;
  const float* W = (z == 0) ? w1 : (z == 1) ? w2 : (z == 2) ? w3 : w4;
  unsigned short* O = (z == 0) ? o1 : (z == 1) ? o2 : (z == 2) ? o3 : o4;
  const int k0 = blockIdx.y * 64, n0 = blockIdx.x * 64;
  const int t = threadIdx.x;
  const int r = t >> 4, c4 = (t & 15) * 4;
  #pragma unroll
  for (int rr = 0; rr < 4; rr++) {
    const int k = rr * 16 + r;
    float4 v = *(const float4*)&W[(long)(k0 + k) * 2048 + n0 + c4];
    T[(c4 + 0) * 72 + k] = f2bf(v.x);
    T[(c4 + 1) * 72 + k] = f2bf(v.y);
    T[(c4 + 2) * 72 + k] = f2bf(v.z);
    T[(c4 + 3) * 72 + k] = f2bf(v.w);
  }
  __syncthreads();
  const int n = t >> 3, k8 = (t & 7) * 8;
  *(uint4*)&O[(long)(n0 + n) * K + k0 + k8]      = *(const uint4*)&T[n * 72 + k8];
  *(uint4*)&O[(long)(n0 + n + 32) * K + k0 + k8] = *(const uint4*)&T[(n + 32) * 72 + k8];
}

// ---------------- prep: idx, tok, mean_obj, LN1 over 4096, write bf16 X ----------------
__global__ __launch_bounds__(256)
void prep_kernel(const float* __restrict__ x_embed, const float* __restrict__ obj,
                 const int* __restrict__ mask, const int* __restrict__ nobj,
                 const float* __restrict__ g, const float* __restrict__ bb,
                 int* __restrict__ idx_out, float* __restrict__ tok_out,
                 unsigned short* __restrict__ xln_out) {
  __shared__ int s_idx;
  __shared__ float sbuf[10];
  const int b = blockIdx.x, t = threadIdx.x;
  if (t == 0) s_idx = 0;
  __syncthreads();
  for (int j = t; j < S_; j += 256)
    if (mask[b * S_ + j] != 0) atomicMax(&s_idx, j);
  __syncthreads();
  const int idx = s_idx;
  if (t == 0) idx_out[b] = idx;

  const float4* tokrow = (const float4*)(x_embed + ((long)b * S_ + idx) * D_);
  float4 t0 = tokrow[t * 2];
  float4 t1 = tokrow[t * 2 + 1];
  ((float4*)(tok_out + (long)b * D_))[t * 2] = t0;
  ((float4*)(tok_out + (long)b * D_))[t * 2 + 1] = t1;

  const int n = nobj[b];
  const float inv_n = 1.0f / (float)n;
  float4 s0 = make_float4(0.f, 0.f, 0.f, 0.f), s1 = s0;
  for (int o = 0; o < n; o++) {
    const float4* orow = (const float4*)(obj + ((long)b * 4 + o) * D_);
    float4 q0 = orow[t * 2], q1 = orow[t * 2 + 1];
    s0.x += q0.x; s0.y += q0.y; s0.z += q0.z; s0.w += q0.w;
    s1.x += q1.x; s1.y += q1.y; s1.z += q1.z; s1.w += q1.w;
  }
  float vals[16] = { t0.x, t0.y, t0.z, t0.w, t1.x, t1.y, t1.z, t1.w,
                     s0.x * inv_n, s0.y * inv_n, s0.z * inv_n, s0.w * inv_n,
                     s1.x * inv_n, s1.y * inv_n, s1.z * inv_n, s1.w * inv_n };
  float sum = 0.f, sq = 0.f;
  #pragma unroll
  for (int i = 0; i < 16; i++) { sum += vals[i]; sq += vals[i] * vals[i]; }
  blockReduce2(sum, sq, sbuf);
  const float mu = sum * (1.f / 4096.f);
  const float rstd = rsqrtf(sq * (1.f / 4096.f) - mu * mu + EPS_);
  #pragma unroll
  for (int i = 0; i < 16; i++) {
    int d = (i < 8) ? (t * 8 + i) : (D_ + t * 8 + (i - 8));
    float v = (vals[i] - mu) * rstd * g[d] + bb[d];
    xln_out[(long)b * (2 * D_) + d] = f2bf(v);
  }
}

// ---------------- pipelined bf16 MFMA GEMM + fused output-copy workers ----------------
// out = epi(A[MxK](bf16) @ Wt[NxK](bf16)^T + bias); blocks with blockIdx.y >= M/64 copy
// a chunk of inputs_embeds -> d_out (hides the 646 MB bulk copy under the GEMM chain).
template<int GELU, int HAS_RES, int OUT_BF16>
__global__ __launch_bounds__(256)
void gemm_kernel(const unsigned short* __restrict__ A, const unsigned short* __restrict__ Wt,
                 const float* __restrict__ bias, const float* __restrict__ res,
                 void* __restrict__ outp, int M, int N, int K,
                 const float4* __restrict__ csrc, float4* __restrict__ cdst, long cn4) {
  const int mblocks = M >> 6;
  if ((int)blockIdx.y >= mblocks) {
    // ---- copy worker ----
    const int cby = gridDim.y - mblocks;
    long i = ((long)((int)blockIdx.y - mblocks) * gridDim.x + blockIdx.x) * blockDim.x + threadIdx.x;
    const long stride = (long)cby * gridDim.x * blockDim.x;
    for (; i < cn4; i += stride) cdst[i] = csrc[i];
    return;
  }
  constexpr int LDA = 72;  // 144 B rows: 16B-aligned, rotates banks by 1 slot/row
  __shared__ __align__(16) unsigned short As[2][64 * LDA];
  __shared__ __align__(16) unsigned short Bs[2][64 * LDA];
  const int tid = threadIdx.x;
  const int m0 = blockIdx.y * 64;
  const int n0 = blockIdx.x * 64;
  const int lane = tid & 63;
  const int wave = tid >> 6;
  const int l16 = lane & 15;
  const int quad = lane >> 4;
  const int wm = (wave & 1) * 32;
  const int wn = (wave >> 1) * 32;
  const int srow = tid >> 3;        // 0..31
  const int scol = (tid & 7) * 8;   // 0..56 (bf16 elems)

  const unsigned short* Ar0 = A  + (long)(m0 + srow) * K + scol;
  const unsigned short* Ar1 = A  + (long)(m0 + srow + 32) * K + scol;
  const unsigned short* Br0 = Wt + (long)(n0 + srow) * K + scol;
  const unsigned short* Br1 = Wt + (long)(n0 + srow + 32) * K + scol;

  f32x4 acc[2][2];
  #pragma unroll
  for (int i = 0; i < 2; i++)
    #pragma unroll
    for (int j = 0; j < 2; j++) acc[i][j] = (f32x4){0.f, 0.f, 0.f, 0.f};

  const int ntile = K >> 6;

  // prologue: tile0 -> buf0; tile1 -> regs (in flight)
  uint4 ra0 = *(const uint4*)Ar0, ra1 = *(const uint4*)Ar1;
  uint4 rb0 = *(const uint4*)Br0, rb1 = *(const uint4*)Br1;
  *(uint4*)&As[0][srow * LDA + scol]        = ra0;
  *(uint4*)&As[0][(srow + 32) * LDA + scol] = ra1;
  *(uint4*)&Bs[0][srow * LDA + scol]        = rb0;
  *(uint4*)&Bs[0][(srow + 32) * LDA + scol] = rb1;
  if (ntile > 1) {
    ra0 = *(const uint4*)(Ar0 + 64); ra1 = *(const uint4*)(Ar1 + 64);
    rb0 = *(const uint4*)(Br0 + 64); rb1 = *(const uint4*)(Br1 + 64);
  }
  __syncthreads();

  for (int t = 0; t < ntile; ++t) {
    const unsigned short* as = As[t & 1];
    const unsigned short* bs = Bs[t & 1];
    // read all fragments for this tile
    bf16x8 af[2][2], bg[2][2];  // [kk][tile]
    #pragma unroll
    for (int kk = 0; kk < 2; kk++) {
      af[kk][0] = *(const bf16x8*)&as[(wm + l16) * LDA + kk * 32 + quad * 8];
      af[kk][1] = *(const bf16x8*)&as[(wm + 16 + l16) * LDA + kk * 32 + quad * 8];
      bg[kk][0] = *(const bf16x8*)&bs[(wn + l16) * LDA + kk * 32 + quad * 8];
      bg[kk][1] = *(const bf16x8*)&bs[(wn + 16 + l16) * LDA + kk * 32 + quad * 8];
    }
    // stage next tile into other buffer; prefetch tile t+2 into regs
    if (t + 1 < ntile) {
      unsigned short* an = As[(t + 1) & 1];
      unsigned short* bn = Bs[(t + 1) & 1];
      *(uint4*)&an[srow * LDA + scol]        = ra0;
      *(uint4*)&an[(srow + 32) * LDA + scol] = ra1;
      *(uint4*)&bn[srow * LDA + scol]        = rb0;
      *(uint4*)&bn[(srow + 32) * LDA + scol] = rb1;
      if (t + 2 < ntile) {
        const int off = (t + 2) << 6;
        ra0 = *(const uint4*)(Ar0 + off); ra1 = *(const uint4*)(Ar1 + off);
        rb0 = *(const uint4*)(Br0 + off); rb1 = *(const uint4*)(Br1 + off);
      }
    }
    #pragma unroll
    for (int kk = 0; kk < 2; kk++)
      #pragma unroll
      for (int mt = 0; mt < 2; mt++)
        #pragma unroll
        for (int nt2 = 0; nt2 < 2; nt2++)
          acc[mt][nt2] = __builtin_amdgcn_mfma_f32_16x16x32_bf16(af[kk][mt], bg[kk][nt2], acc[mt][nt2], 0, 0, 0);
    __syncthreads();
  }
  // epilogue: C/D layout col=lane&15, row=quad*4+r
  #pragma unroll
  for (int mt = 0; mt < 2; mt++) {
    #pragma unroll
    for (int nt2 = 0; nt2 < 2; nt2++) {
      const int col = n0 + wn + nt2 * 16 + l16;
      const float bc = bias[col];
      #pragma unroll
      for (int r = 0; r < 4; r++) {
        const int row = m0 + wm + mt * 16 + quad * 4 + r;
        float v = acc[mt][nt2][r] + bc;
        if constexpr (HAS_RES) v += res[(long)row * N + col];
        if constexpr (GELU) v = 0.5f * v * (1.f + erff(v * 0.70710678118654752f));
        if constexpr (OUT_BF16)
          ((unsigned short*)outp)[(long)row * N + col] = f2bf(v);
        else
          ((float*)outp)[(long)row * N + col] = v;
      }
    }
  }
}

// ---------------- LN over 2048, bf16 out (mlp2 input) ----------------
__global__ __launch_bounds__(256)
void ln_bf16_kernel(const float* __restrict__ in, const float* __restrict__ g,
                    const float* __restrict__ bb, unsigned short* __restrict__ out) {
  __shared__ float sbuf[10];
  const int b = blockIdx.x, t = threadIdx.x;
  const float4* row = (const float4*)(in + (long)b * D_);
  float4 v0 = row[t * 2], v1 = row[t * 2 + 1];
  float o[8] = { v0.x, v0.y, v0.z, v0.w, v1.x, v1.y, v1.z, v1.w };
  float sum = 0.f, sq = 0.f;
  #pragma unroll
  for (int i = 0; i < 8; i++) { sum += o[i]; sq += o[i] * o[i]; }
  blockReduce2(sum, sq, sbuf);
  const float mu = sum * (1.f / 2048.f);
  const float rstd = rsqrtf(sq * (1.f / 2048.f) - mu * mu + EPS_);
  const int d0 = t * 8;
  #pragma unroll
  for (int i = 0; i < 8; i++)
    out[(long)b * D_ + d0 + i] = f2bf((o[i] - mu) * rstd * g[d0 + i] + bb[d0 + i]);
}

// ---------------- final LN + scatter into out[b, idx[b], :] ----------------
__global__ __launch_bounds__(256)
void final_kernel(const float* __restrict__ in, const float* __restrict__ g,
                  const float* __restrict__ bb, const int* __restrict__ idxbuf,
                  float* __restrict__ out) {
  __shared__ float sbuf[10];
  const int b = blockIdx.x, t = threadIdx.x;
  const float4* row = (const float4*)(in + (long)b * D_);
  float4 v0 = row[t * 2], v1 = row[t * 2 + 1];
  float o[8] = { v0.x, v0.y, v0.z, v0.w, v1.x, v1.y, v1.z, v1.w };
  float sum = 0.f, sq = 0.f;
  #pragma unroll
  for (int i = 0; i < 8; i++) { sum += o[i]; sq += o[i] * o[i]; }
  blockReduce2(sum, sq, sbuf);
  const float mu = sum * (1.f / 2048.f);
  const float rstd = rsqrtf(sq * (1.f / 2048.f) - mu * mu + EPS_);
  float* orow = out + ((long)b * S_ + idxbuf[b]) * D_;
  const int d0 = t * 8;
  #pragma unroll
  for (int i = 0; i < 8; i++) o[i] = (o[i] - mu) * rstd * g[d0 + i] + bb[d0 + i];
  ((float4*)orow)[t * 2]     = make_float4(o[0], o[1], o[2], o[3]);
  ((float4*)orow)[t * 2 + 1] = make_float4(o[4], o[5], o[6], o[7]);
}

extern "C" void kernel_launch(void* const* d_in, const int* in_sizes, int n_in,
                              void* d_out, int out_size, void* d_ws, size_t ws_size,
                              hipStream_t stream) {
  const float* inputs_embeds = (const float*)d_in[0];
  const float* object_embeds = (const float*)d_in[1];
  const float* mlp1_ln_g = (const float*)d_in[2];
  const float* mlp1_ln_b = (const float*)d_in[3];
  const float* mlp1_w1   = (const float*)d_in[4];
  const float* mlp1_b1   = (const float*)d_in[5];
  const float* mlp1_w2   = (const float*)d_in[6];
  const float* mlp1_b2   = (const float*)d_in[7];
  const float* mlp2_ln_g = (const float*)d_in[8];
  const float* mlp2_ln_b = (const float*)d_in[9];
  const float* mlp2_w1   = (const float*)d_in[10];
  const float* mlp2_b1   = (const float*)d_in[11];
  const float* mlp2_w2   = (const float*)d_in[12];
  const float* mlp2_b2   = (const float*)d_in[13];
  const float* ln_g      = (const float*)d_in[14];
  const float* ln_b      = (const float*)d_in[15];
  const int* mask        = (const int*)d_in[16];
  const int* nobj        = (const int*)d_in[17];

  char* ws = (char*)d_ws;
  int*            idxbuf = (int*)ws;                                   // 512 ints
  float*          tok    = (float*)(ws + 4096);                        // 512x2048 f32
  unsigned short* xln    = (unsigned short*)(ws + 4096 + 4194304);     // 512x4096 bf16
  unsigned short* h1     = (unsigned short*)(ws + 4096 + 8388608);     // 512x2048 bf16
  float*          h2     = (float*)(ws + 4096 + 10485760);             // 512x2048 f32
  unsigned short* x2ln   = (unsigned short*)(ws + 4096 + 14680064);    // 512x2048 bf16
  unsigned short* h3     = (unsigned short*)(ws + 4096 + 16777216);    // 512x2048 bf16
  float*          h4     = (float*)(ws + 4096 + 18874368);             // 512x2048 f32
  char*           wbase  = ws + 4096 + 18874368 + 4194304;             // bf16 Wt buffers
  unsigned short* w1t    = (unsigned short*)(wbase);                   // 2048x4096 bf16 (16 MB)
  unsigned short* w2t    = (unsigned short*)(wbase + 16777216);        // 2048x2048 bf16 (8 MB)
  unsigned short* w3t    = (unsigned short*)(wbase + 25165824);        // 2048x2048 bf16 (8 MB)
  unsigned short* w4t    = (unsigned short*)(wbase + 33554432);        // 2048x2048 bf16 (8 MB)

  // weights -> bf16 transposed [N][K] (one launch for all four)
  wcvt_kernel<<<dim3(32, 64, 4), 256, 0, stream>>>(mlp1_w1, mlp1_w2, mlp2_w1, mlp2_w2,
                                                   w1t, w2t, w3t, w4t);

  prep_kernel<<<B_, 256, 0, stream>>>(inputs_embeds, object_embeds, mask, nobj,
                                      mlp1_ln_g, mlp1_ln_b, idxbuf, tok, xln);

  // bulk output copy (646 MB) split into 4 chunks, hidden inside the 4 GEMM launches
  const float4* in4 = (const float4*)inputs_embeds;
  float4* out4 = (float4*)d_out;
  const long n4 = (long)B_ * S_ * D_ / 4;       // 20,185,088
  const long ch = n4 / 4;                       // 5,046,272 (exact)

  dim3 gg(2048 / 64, B_ / 64 + 8);  // 8 compute rows + 8 copy-worker rows
  gemm_kernel<1, 0, 1><<<gg, 256, 0, stream>>>(xln,  w1t, mlp1_b1, nullptr, h1, B_, D_, 2 * D_,
                                               in4 + 0 * ch, out4 + 0 * ch, ch);
  gemm_kernel<0, 1, 0><<<gg, 256, 0, stream>>>(h1,   w2t, mlp1_b2, tok,     h2, B_, D_, D_,
                                               in4 + 1 * ch, out4 + 1 * ch, ch);
  ln_bf16_kernel<<<B_, 256, 0, stream>>>(h2, mlp2_ln_g, mlp2_ln_b, x2ln);
  gemm_kernel<1, 0, 1><<<gg, 256, 0, stream>>>(x2ln, w3t, mlp2_b1, nullptr, h3, B_, D_, D_,
                                               in4 + 2 * ch, out4 + 2 * ch, ch);
  gemm_kernel<0, 1, 0><<<gg, 256, 0, stream>>>(h3,   w4t, mlp2_b2, h2,      h4, B_, D_, D_,
                                               in4 + 3 * ch, out4 + 3 * ch, ch);
  final_kernel<<<B_, 256, 0, stream>>>(h4, ln_g, ln_b, idxbuf, (float*)d_out);
}

// Round 2
// 680.886 us; speedup vs baseline: 1.2752x; 1.0677x over previous
//
#include <hip/hip_runtime.h>
#include <math.h>

// Problem constants (B, S, D, MAXOBJ) = (512, 77, 2048, 4)
#define B_ 512
#define S_ 77
#define D_ 2048
#define EPS_ 1e-5f

typedef __attribute__((ext_vector_type(8))) short bf16x8;
typedef __attribute__((ext_vector_type(4))) float f32x4;

// fp32 -> bf16 bits, round-to-nearest-even
__device__ __forceinline__ unsigned short f2bf(float f) {
  union { float f; unsigned u; } x; x.f = f;
  return (unsigned short)((x.u + 0x7FFFu + ((x.u >> 16) & 1u)) >> 16);
}

// block=256 reduction of (sum, sumsq)
__device__ __forceinline__ void blockReduce2(float& a, float& b, float* sbuf) {
  #pragma unroll
  for (int off = 32; off > 0; off >>= 1) {
    a += __shfl_down(a, off, 64);
    b += __shfl_down(b, off, 64);
  }
  int lane = threadIdx.x & 63, wid = threadIdx.x >> 6;
  if (lane == 0) { sbuf[wid * 2] = a; sbuf[wid * 2 + 1] = b; }
  __syncthreads();
  if (threadIdx.x == 0) {
    float sa = 0.f, sb = 0.f;
    #pragma unroll
    for (int w = 0; w < 4; w++) { sa += sbuf[w * 2]; sb += sbuf[w * 2 + 1]; }
    sbuf[8] = sa; sbuf[9] = sb;
  }
  __syncthreads();
  a = sbuf[8]; b = sbuf[9];
}

// ---------------- merged: weight convert+transpose (z=0..3) and prep (z=4) ----------------
// wcvt: W[K][2048] f32 -> Wt[2048][K] bf16.  prep: idx, tok, mean_obj, LN over 4096 -> bf16 X.
__global__ __launch_bounds__(256)
void prep_wcvt_kernel(const float* __restrict__ w1, const float* __restrict__ w2,
                      const float* __restrict__ w3, const float* __restrict__ w4,
                      unsigned short* __restrict__ o1, unsigned short* __restrict__ o2,
                      unsigned short* __restrict__ o3, unsigned short* __restrict__ o4,
                      const float* __restrict__ x_embed, const float* __restrict__ obj,
                      const int* __restrict__ mask, const int* __restrict__ nobj,
                      const float* __restrict__ g, const float* __restrict__ bb,
                      int* __restrict__ idx_out, float* __restrict__ tok_out,
                      unsigned short* __restrict__ xln_out) {
  __shared__ unsigned short T[64 * 72];
  __shared__ int s_idx;
  __shared__ float sbuf[10];
  const int z = blockIdx.z;
  const int t = threadIdx.x;

  if (z == 4) {
    // ---------------- prep path ----------------
    const int b = blockIdx.y * gridDim.x + blockIdx.x;
    if (b >= B_) return;
    if (t == 0) s_idx = 0;
    __syncthreads();
    for (int j = t; j < S_; j += 256)
      if (mask[b * S_ + j] != 0) atomicMax(&s_idx, j);
    __syncthreads();
    const int idx = s_idx;
    if (t == 0) idx_out[b] = idx;

    const float4* tokrow = (const float4*)(x_embed + ((long)b * S_ + idx) * D_);
    float4 t0 = tokrow[t * 2];
    float4 t1 = tokrow[t * 2 + 1];
    ((float4*)(tok_out + (long)b * D_))[t * 2] = t0;
    ((float4*)(tok_out + (long)b * D_))[t * 2 + 1] = t1;

    const int n = nobj[b];
    const float inv_n = 1.0f / (float)n;
    float4 s0 = make_float4(0.f, 0.f, 0.f, 0.f), s1 = s0;
    for (int o = 0; o < n; o++) {
      const float4* orow = (const float4*)(obj + ((long)b * 4 + o) * D_);
      float4 q0 = orow[t * 2], q1 = orow[t * 2 + 1];
      s0.x += q0.x; s0.y += q0.y; s0.z += q0.z; s0.w += q0.w;
      s1.x += q1.x; s1.y += q1.y; s1.z += q1.z; s1.w += q1.w;
    }
    float vals[16] = { t0.x, t0.y, t0.z, t0.w, t1.x, t1.y, t1.z, t1.w,
                       s0.x * inv_n, s0.y * inv_n, s0.z * inv_n, s0.w * inv_n,
                       s1.x * inv_n, s1.y * inv_n, s1.z * inv_n, s1.w * inv_n };
    float sum = 0.f, sq = 0.f;
    #pragma unroll
    for (int i = 0; i < 16; i++) { sum += vals[i]; sq += vals[i] * vals[i]; }
    blockReduce2(sum, sq, sbuf);
    const float mu = sum * (1.f / 4096.f);
    const float rstd = rsqrtf(sq * (1.f / 4096.f) - mu * mu + EPS_);
    #pragma unroll
    for (int i = 0; i < 16; i++) {
      int d = (i < 8) ? (t * 8 + i) : (D_ + t * 8 + (i - 8));
      float v = (vals[i] - mu) * rstd * g[d] + bb[d];
      xln_out[(long)b * (2 * D_) + d] = f2bf(v);
    }
    return;
  }

  // ---------------- wcvt path ----------------
  const int K = (z == 0) ? 4096 : 2048;
  if ((int)blockIdx.y * 64 >= K) return;
  const float* W = (z == 0) ? w1 : (z == 1) ? w2 : (z == 2) ? w3 : w4;
  unsigned short* O = (z == 0) ? o1 : (z == 1) ? o2 : (z == 2) ? o3 : o4;
  const int k0 = blockIdx.y * 64, n0 = blockIdx.x * 64;
  const int r = t >> 4, c4 = (t & 15) * 4;
  #pragma unroll
  for (int rr = 0; rr < 4; rr++) {
    const int k = rr * 16 + r;
    float4 v = *(const float4*)&W[(long)(k0 + k) * 2048 + n0 + c4];
    T[(c4 + 0) * 72 + k] = f2bf(v.x);
    T[(c4 + 1) * 72 + k] = f2bf(v.y);
    T[(c4 + 2) * 72 + k] = f2bf(v.z);
    T[(c4 + 3) * 72 + k] = f2bf(v.w);
  }
  __syncthreads();
  const int n = t >> 3, k8 = (t & 7) * 8;
  *(uint4*)&O[(long)(n0 + n) * K + k0 + k8]      = *(const uint4*)&T[n * 72 + k8];
  *(uint4*)&O[(long)(n0 + n + 32) * K + k0 + k8] = *(const uint4*)&T[(n + 32) * 72 + k8];
}

// ---------------- pipelined bf16 MFMA GEMM + fused output-copy workers ----------------
// out = epi(A[MxK](bf16) @ Wt[NxK](bf16)^T + bias); blocks with blockIdx.y >= M/64 copy
// a chunk of inputs_embeds -> d_out. Copy workers keep 4 loads in flight (MLP=4) and
// use 16 grid rows so the copy stays HBM-BW-bound, not latency-bound.
template<int GELU, int HAS_RES, int OUT_BF16>
__global__ __launch_bounds__(256)
void gemm_kernel(const unsigned short* __restrict__ A, const unsigned short* __restrict__ Wt,
                 const float* __restrict__ bias, const float* __restrict__ res,
                 void* __restrict__ outp, int M, int N, int K,
                 const float4* __restrict__ csrc, float4* __restrict__ cdst, long cn4) {
  const int mblocks = M >> 6;
  if ((int)blockIdx.y >= mblocks) {
    // ---- copy worker: 4 independent loads in flight per iteration ----
    const int cby = gridDim.y - mblocks;
    const long tcount = (long)cby * gridDim.x * blockDim.x;
    long i = ((long)((int)blockIdx.y - mblocks) * gridDim.x + blockIdx.x) * blockDim.x + threadIdx.x;
    const long lim = cn4 - 3 * tcount;
    for (; i < lim; i += 4 * tcount) {
      float4 v0 = csrc[i];
      float4 v1 = csrc[i + tcount];
      float4 v2 = csrc[i + 2 * tcount];
      float4 v3 = csrc[i + 3 * tcount];
      cdst[i] = v0;
      cdst[i + tcount] = v1;
      cdst[i + 2 * tcount] = v2;
      cdst[i + 3 * tcount] = v3;
    }
    for (; i < cn4; i += tcount) cdst[i] = csrc[i];
    return;
  }
  constexpr int LDA = 72;  // 144 B rows: 16B-aligned, rotates banks by 1 slot/row
  __shared__ __align__(16) unsigned short As[2][64 * LDA];
  __shared__ __align__(16) unsigned short Bs[2][64 * LDA];
  const int tid = threadIdx.x;
  const int m0 = blockIdx.y * 64;
  const int n0 = blockIdx.x * 64;
  const int lane = tid & 63;
  const int wave = tid >> 6;
  const int l16 = lane & 15;
  const int quad = lane >> 4;
  const int wm = (wave & 1) * 32;
  const int wn = (wave >> 1) * 32;
  const int srow = tid >> 3;        // 0..31
  const int scol = (tid & 7) * 8;   // 0..56 (bf16 elems)

  const unsigned short* Ar0 = A  + (long)(m0 + srow) * K + scol;
  const unsigned short* Ar1 = A  + (long)(m0 + srow + 32) * K + scol;
  const unsigned short* Br0 = Wt + (long)(n0 + srow) * K + scol;
  const unsigned short* Br1 = Wt + (long)(n0 + srow + 32) * K + scol;

  f32x4 acc[2][2];
  #pragma unroll
  for (int i = 0; i < 2; i++)
    #pragma unroll
    for (int j = 0; j < 2; j++) acc[i][j] = (f32x4){0.f, 0.f, 0.f, 0.f};

  const int ntile = K >> 6;

  // prologue: tile0 -> buf0; tile1 -> regs (in flight)
  uint4 ra0 = *(const uint4*)Ar0, ra1 = *(const uint4*)Ar1;
  uint4 rb0 = *(const uint4*)Br0, rb1 = *(const uint4*)Br1;
  *(uint4*)&As[0][srow * LDA + scol]        = ra0;
  *(uint4*)&As[0][(srow + 32) * LDA + scol] = ra1;
  *(uint4*)&Bs[0][srow * LDA + scol]        = rb0;
  *(uint4*)&Bs[0][(srow + 32) * LDA + scol] = rb1;
  if (ntile > 1) {
    ra0 = *(const uint4*)(Ar0 + 64); ra1 = *(const uint4*)(Ar1 + 64);
    rb0 = *(const uint4*)(Br0 + 64); rb1 = *(const uint4*)(Br1 + 64);
  }
  __syncthreads();

  for (int t = 0; t < ntile; ++t) {
    const unsigned short* as = As[t & 1];
    const unsigned short* bs = Bs[t & 1];
    // read all fragments for this tile
    bf16x8 af[2][2], bg[2][2];  // [kk][tile]
    #pragma unroll
    for (int kk = 0; kk < 2; kk++) {
      af[kk][0] = *(const bf16x8*)&as[(wm + l16) * LDA + kk * 32 + quad * 8];
      af[kk][1] = *(const bf16x8*)&as[(wm + 16 + l16) * LDA + kk * 32 + quad * 8];
      bg[kk][0] = *(const bf16x8*)&bs[(wn + l16) * LDA + kk * 32 + quad * 8];
      bg[kk][1] = *(const bf16x8*)&bs[(wn + 16 + l16) * LDA + kk * 32 + quad * 8];
    }
    // stage next tile into other buffer; prefetch tile t+2 into regs
    if (t + 1 < ntile) {
      unsigned short* an = As[(t + 1) & 1];
      unsigned short* bn = Bs[(t + 1) & 1];
      *(uint4*)&an[srow * LDA + scol]        = ra0;
      *(uint4*)&an[(srow + 32) * LDA + scol] = ra1;
      *(uint4*)&bn[srow * LDA + scol]        = rb0;
      *(uint4*)&bn[(srow + 32) * LDA + scol] = rb1;
      if (t + 2 < ntile) {
        const int off = (t + 2) << 6;
        ra0 = *(const uint4*)(Ar0 + off); ra1 = *(const uint4*)(Ar1 + off);
        rb0 = *(const uint4*)(Br0 + off); rb1 = *(const uint4*)(Br1 + off);
      }
    }
    #pragma unroll
    for (int kk = 0; kk < 2; kk++)
      #pragma unroll
      for (int mt = 0; mt < 2; mt++)
        #pragma unroll
        for (int nt2 = 0; nt2 < 2; nt2++)
          acc[mt][nt2] = __builtin_amdgcn_mfma_f32_16x16x32_bf16(af[kk][mt], bg[kk][nt2], acc[mt][nt2], 0, 0, 0);
    __syncthreads();
  }
  // epilogue: C/D layout col=lane&15, row=quad*4+r
  #pragma unroll
  for (int mt = 0; mt < 2; mt++) {
    #pragma unroll
    for (int nt2 = 0; nt2 < 2; nt2++) {
      const int col = n0 + wn + nt2 * 16 + l16;
      const float bc = bias[col];
      #pragma unroll
      for (int r = 0; r < 4; r++) {
        const int row = m0 + wm + mt * 16 + quad * 4 + r;
        float v = acc[mt][nt2][r] + bc;
        if constexpr (HAS_RES) v += res[(long)row * N + col];
        if constexpr (GELU) v = 0.5f * v * (1.f + erff(v * 0.70710678118654752f));
        if constexpr (OUT_BF16)
          ((unsigned short*)outp)[(long)row * N + col] = f2bf(v);
        else
          ((float*)outp)[(long)row * N + col] = v;
      }
    }
  }
}

// ---------------- LN over 2048, bf16 out (mlp2 input) ----------------
__global__ __launch_bounds__(256)
void ln_bf16_kernel(const float* __restrict__ in, const float* __restrict__ g,
                    const float* __restrict__ bb, unsigned short* __restrict__ out) {
  __shared__ float sbuf[10];
  const int b = blockIdx.x, t = threadIdx.x;
  const float4* row = (const float4*)(in + (long)b * D_);
  float4 v0 = row[t * 2], v1 = row[t * 2 + 1];
  float o[8] = { v0.x, v0.y, v0.z, v0.w, v1.x, v1.y, v1.z, v1.w };
  float sum = 0.f, sq = 0.f;
  #pragma unroll
  for (int i = 0; i < 8; i++) { sum += o[i]; sq += o[i] * o[i]; }
  blockReduce2(sum, sq, sbuf);
  const float mu = sum * (1.f / 2048.f);
  const float rstd = rsqrtf(sq * (1.f / 2048.f) - mu * mu + EPS_);
  const int d0 = t * 8;
  #pragma unroll
  for (int i = 0; i < 8; i++)
    out[(long)b * D_ + d0 + i] = f2bf((o[i] - mu) * rstd * g[d0 + i] + bb[d0 + i]);
}

// ---------------- final LN + scatter into out[b, idx[b], :] ----------------
__global__ __launch_bounds__(256)
void final_kernel(const float* __restrict__ in, const float* __restrict__ g,
                  const float* __restrict__ bb, const int* __restrict__ idxbuf,
                  float* __restrict__ out) {
  __shared__ float sbuf[10];
  const int b = blockIdx.x, t = threadIdx.x;
  const float4* row = (const float4*)(in + (long)b * D_);
  float4 v0 = row[t * 2], v1 = row[t * 2 + 1];
  float o[8] = { v0.x, v0.y, v0.z, v0.w, v1.x, v1.y, v1.z, v1.w };
  float sum = 0.f, sq = 0.f;
  #pragma unroll
  for (int i = 0; i < 8; i++) { sum += o[i]; sq += o[i] * o[i]; }
  blockReduce2(sum, sq, sbuf);
  const float mu = sum * (1.f / 2048.f);
  const float rstd = rsqrtf(sq * (1.f / 2048.f) - mu * mu + EPS_);
  float* orow = out + ((long)b * S_ + idxbuf[b]) * D_;
  const int d0 = t * 8;
  #pragma unroll
  for (int i = 0; i < 8; i++) o[i] = (o[i] - mu) * rstd * g[d0 + i] + bb[d0 + i];
  ((float4*)orow)[t * 2]     = make_float4(o[0], o[1], o[2], o[3]);
  ((float4*)orow)[t * 2 + 1] = make_float4(o[4], o[5], o[6], o[7]);
}

extern "C" void kernel_launch(void* const* d_in, const int* in_sizes, int n_in,
                              void* d_out, int out_size, void* d_ws, size_t ws_size,
                              hipStream_t stream) {
  const float* inputs_embeds = (const float*)d_in[0];
  const float* object_embeds = (const float*)d_in[1];
  const float* mlp1_ln_g = (const float*)d_in[2];
  const float* mlp1_ln_b = (const float*)d_in[3];
  const float* mlp1_w1   = (const float*)d_in[4];
  const float* mlp1_b1   = (const float*)d_in[5];
  const float* mlp1_w2   = (const float*)d_in[6];
  const float* mlp1_b2   = (const float*)d_in[7];
  const float* mlp2_ln_g = (const float*)d_in[8];
  const float* mlp2_ln_b = (const float*)d_in[9];
  const float* mlp2_w1   = (const float*)d_in[10];
  const float* mlp2_b1   = (const float*)d_in[11];
  const float* mlp2_w2   = (const float*)d_in[12];
  const float* mlp2_b2   = (const float*)d_in[13];
  const float* ln_g      = (const float*)d_in[14];
  const float* ln_b      = (const float*)d_in[15];
  const int* mask        = (const int*)d_in[16];
  const int* nobj        = (const int*)d_in[17];

  char* ws = (char*)d_ws;
  int*            idxbuf = (int*)ws;                                   // 512 ints
  float*          tok    = (float*)(ws + 4096);                        // 512x2048 f32
  unsigned short* xln    = (unsigned short*)(ws + 4096 + 4194304);     // 512x4096 bf16
  unsigned short* h1     = (unsigned short*)(ws + 4096 + 8388608);     // 512x2048 bf16
  float*          h2     = (float*)(ws + 4096 + 10485760);             // 512x2048 f32
  unsigned short* x2ln   = (unsigned short*)(ws + 4096 + 14680064);    // 512x2048 bf16
  unsigned short* h3     = (unsigned short*)(ws + 4096 + 16777216);    // 512x2048 bf16
  float*          h4     = (float*)(ws + 4096 + 18874368);             // 512x2048 f32
  char*           wbase  = ws + 4096 + 18874368 + 4194304;             // bf16 Wt buffers
  unsigned short* w1t    = (unsigned short*)(wbase);                   // 2048x4096 bf16 (16 MB)
  unsigned short* w2t    = (unsigned short*)(wbase + 16777216);        // 2048x2048 bf16 (8 MB)
  unsigned short* w3t    = (unsigned short*)(wbase + 25165824);        // 2048x2048 bf16 (8 MB)
  unsigned short* w4t    = (unsigned short*)(wbase + 33554432);        // 2048x2048 bf16 (8 MB)

  // weights -> bf16 transposed [N][K] (z=0..3) + prep (z=4), one launch
  prep_wcvt_kernel<<<dim3(32, 64, 5), 256, 0, stream>>>(
      mlp1_w1, mlp1_w2, mlp2_w1, mlp2_w2, w1t, w2t, w3t, w4t,
      inputs_embeds, object_embeds, mask, nobj, mlp1_ln_g, mlp1_ln_b,
      idxbuf, tok, xln);

  // bulk output copy (646 MB) split into 4 chunks, hidden inside the 4 GEMM launches
  const float4* in4 = (const float4*)inputs_embeds;
  float4* out4 = (float4*)d_out;
  const long n4 = (long)B_ * S_ * D_ / 4;       // 20,185,088
  const long ch = n4 / 4;                       // 5,046,272 (exact)

  dim3 gg(2048 / 64, B_ / 64 + 16);  // 8 compute rows + 16 copy-worker rows
  gemm_kernel<1, 0, 1><<<gg, 256, 0, stream>>>(xln,  w1t, mlp1_b1, nullptr, h1, B_, D_, 2 * D_,
                                               in4 + 0 * ch, out4 + 0 * ch, ch);
  gemm_kernel<0, 1, 0><<<gg, 256, 0, stream>>>(h1,   w2t, mlp1_b2, tok,     h2, B_, D_, D_,
                                               in4 + 1 * ch, out4 + 1 * ch, ch);
  ln_bf16_kernel<<<B_, 256, 0, stream>>>(h2, mlp2_ln_g, mlp2_ln_b, x2ln);
  gemm_kernel<1, 0, 1><<<gg, 256, 0, stream>>>(x2ln, w3t, mlp2_b1, nullptr, h3, B_, D_, D_,
                                               in4 + 2 * ch, out4 + 2 * ch, ch);
  gemm_kernel<0, 1, 0><<<gg, 256, 0, stream>>>(h3,   w4t, mlp2_b2, h2,      h4, B_, D_, D_,
                                               in4 + 3 * ch, out4 + 3 * ch, ch);
  final_kernel<<<B_, 256, 0, stream>>>(h4, ln_g, ln_b, idxbuf, (float*)d_out);
}